// Round 1
// baseline (224.395 us; speedup 1.0000x reference)
//
#include <hip/hip_runtime.h>

#define EPS_F 1e-6f
#define MARGIN_F 0.8f

__device__ __forceinline__ float sq8(const float4& a0, const float4& a1,
                                     const float4& b0, const float4& b1) {
    float acc, d;
    d = a0.x - b0.x + EPS_F; acc  = d * d;
    d = a0.y - b0.y + EPS_F; acc += d * d;
    d = a0.z - b0.z + EPS_F; acc += d * d;
    d = a0.w - b0.w + EPS_F; acc += d * d;
    d = a1.x - b1.x + EPS_F; acc += d * d;
    d = a1.y - b1.y + EPS_F; acc += d * d;
    d = a1.z - b1.z + EPS_F; acc += d * d;
    d = a1.w - b1.w + EPS_F; acc += d * d;
    return acc;
}

// One 64-lane wave per row. D = 512 floats = 128 float4; lane reads float4 at
// [lane] and [lane+64] -> two fully coalesced 1 KiB wave transactions per operand.
template<int KV>
__global__ __launch_bounds__(256) void closs_kernel(
    const float* __restrict__ out1,
    const float* __restrict__ vecs,
    const float* __restrict__ feat1,
    const int* __restrict__ label,
    const unsigned* __restrict__ alpha_raw,
    float* __restrict__ loss,
    int Brows)
{
    int gtid = blockIdx.x * blockDim.x + threadIdx.x;
    int row  = gtid >> 6;
    int lane = threadIdx.x & 63;
    if (row >= Brows) return;

    size_t rowOff = (size_t)row * 512;

    const float4* op = (const float4*)(out1 + rowOff);
    float4 o0 = op[lane];
    float4 o1 = op[lane + 64];

    const float4* fp = (const float4*)(feat1 + rowOff);
    float4 f0 = fp[lane];
    float4 f1 = fp[lane + 64];

    float s[KV + 1];
    s[KV] = sq8(o0, o1, f0, f1);

#pragma unroll
    for (int k = 0; k < KV; ++k) {
        const float4* vp = (const float4*)(vecs + ((size_t)k * Brows) * 512 + rowOff);
        float4 v0 = vp[lane];
        float4 v1 = vp[lane + 64];
        s[k] = sq8(o0, o1, v0, v1);
    }

    // Butterfly-reduce each of the KV+1 partial sums across the 64-lane wave.
#pragma unroll
    for (int k = 0; k <= KV; ++k) {
        float v = s[k];
#pragma unroll
        for (int m = 32; m >= 1; m >>= 1)
            v += __shfl_xor(v, m, 64);
        s[k] = v;
    }

    if (lane == 0) {
        // alpha is a 1-element array of harness-chosen dtype (Python scalar).
        // Heuristic decode: if the 32-bit pattern looks like a normal float
        // (exponent in a sane range), read float; else read int (covers
        // int32 and little-endian int64 low word).
        unsigned u = *alpha_raw;
        int e = (int)((u >> 23) & 0xff);
        float alpha;
        if (u != 0u && e >= 100 && e <= 160) alpha = __uint_as_float(u);
        else                                 alpha = (float)(*(const int*)alpha_raw);

        const float inv_sqrt_d = 0.04419417382415922f; // 1/sqrt(512)
        float ed = 0.f;
#pragma unroll
        for (int k = 0; k < KV; ++k) ed += sqrtf(s[k]);
        ed += alpha * sqrtf(s[KV]);
        ed *= inv_sqrt_d;

        float marg  = ((float)KV + alpha) * MARGIN_F;
        float lab   = (float)label[row];
        float hinge = fmaxf(0.f, marg - ed);
        float l = (1.f - lab) * ed * ed * 0.5f + lab * hinge * hinge * 0.5f;
        loss[row] = l;
    }
}

extern "C" void kernel_launch(void* const* d_in, const int* in_sizes, int n_in,
                              void* d_out, int out_size, void* d_ws, size_t ws_size,
                              hipStream_t stream) {
    const float*    out1  = (const float*)d_in[0];
    const float*    vecs  = (const float*)d_in[1];
    const float*    feat1 = (const float*)d_in[2];
    const int*      label = (const int*)d_in[3];
    const unsigned* alpha = (const unsigned*)d_in[4];
    float*          loss  = (float*)d_out;

    int Brows = in_sizes[3];          // label count == B (65536)
    int block = 256;                  // 4 waves -> 4 rows per block
    long long totalThreads = (long long)Brows * 64;
    int grid = (int)((totalThreads + block - 1) / block);

    closs_kernel<8><<<grid, block, 0, stream>>>(out1, vecs, feat1, label, alpha, loss, Brows);
}